// Round 9
// baseline (454.009 us; speedup 1.0000x reference)
//
#include <hip/hip_runtime.h>
#include <hip/hip_fp16.h>

#define D 128

// CSR build geometry (pow-2 so kernels use shifts, not divides)
constexpr int RSH = 14;             // log2(range size)
constexpr int RSZ = 1 << RSH;       // 16384 nodes/range
constexpr int NRANGE = 4;           // ceil(50000/16384)
constexpr int CSH = 15;             // log2(chunk edges)
constexpr int CSZ = 1 << CSH;       // 32768 edges/chunk

using short8 = __attribute__((ext_vector_type(8))) short;
using f32x4 = __attribute__((ext_vector_type(4))) float;

// split fp32 into hi/lo bf16 (truncation; residual exact in fp32)
__device__ inline void splitf(float v, unsigned short& h, unsigned short& l) {
    unsigned b = __float_as_uint(v);
    h = (unsigned short)(b >> 16);
    float fh = __uint_as_float(b & 0xffff0000u);
    float r = v - fh;
    l = (unsigned short)(__float_as_uint(r) >> 16);
}

// ---------------- weight split+transpose: W[K=128][N] -> Wt_hi/lo [N][128] ----------------
struct WSplitArgs {
    const float* src[6];
    unsigned short* dh[6];
    unsigned short* dl[6];
    int n[6];
};

__global__ __launch_bounds__(256) void split_w(WSplitArgs a) {
    int m = blockIdx.y;
    int N = a.n[m];
    int e = blockIdx.x * 256 + threadIdx.x;
    if (e >= 128 * N) return;
    int sh = (N == 128) ? 7 : 6;
    int k = e >> sh;
    int n = e & (N - 1);
    float v = a.src[m][e];
    unsigned short h, l;
    splitf(v, h, l);
    a.dh[m][n * 128 + k] = h;
    a.dl[m][n * 128 + k] = l;
}

// ---------------- fused hist_rank (CSR phase 1) + layer-0 GEMM ----------------
__global__ __launch_bounds__(1024) void hist_gemm_x(
    const int* __restrict__ dst, unsigned* __restrict__ hist,
    unsigned short* __restrict__ rank, int n_edges, int nchunk, int nhist,
    const float* __restrict__ X,
    const unsigned short* __restrict__ W1h, const unsigned short* __restrict__ W1l,
    const unsigned short* __restrict__ W2h, const unsigned short* __restrict__ W2l,
    const float* __restrict__ bias, __half* __restrict__ P, float* __restrict__ Q, int M) {
    __shared__ __align__(16) char smem[2 * 16 * 65 * 16];   // 33280 B (hist needs 32768)

    const int b = blockIdx.x;
    const int tid = threadIdx.x;

    if (b < nhist) {
        // ---- hist_rank path ----
        unsigned* lh = (unsigned*)smem;   // RSZ/2 = 8192 words of packed u16 counts
        int r = b & (NRANGE - 1), c = b >> 2;
        for (int i = tid; i < RSZ / 2; i += 1024) lh[i] = 0;
        __syncthreads();
        int e0 = c << CSH, e1 = min(n_edges, e0 + CSZ);
        for (int e = e0 + tid; e < e1; e += 1024) {
            int d = dst[e];
            if ((d >> RSH) == r) {
                int ii = d & (RSZ - 1);
                unsigned sh = (ii & 1) * 16;
                unsigned old = atomicAdd(&lh[ii >> 1], 1u << sh);
                rank[e] = (unsigned short)((old >> sh) & 0xffffu);
            }
        }
        __syncthreads();
        unsigned* gh = hist + (size_t)(r * nchunk + c) * (RSZ / 2);
        for (int i = tid; i < RSZ / 2; i += 1024) gh[i] = lh[i];
        return;
    }

    // ---- gemm_x path ----
    short8(*As)[16 * 65] = (short8(*)[16 * 65])smem;
    const int wave = tid >> 6;          // 0..15
    const int lane = tid & 63;
    const int l15 = lane & 15;
    const int q = lane >> 4;
    const int m0 = (b - nhist) * 64;

    {   // stage A tile (64 rows x 128 cols fp32 -> bf16 hi/lo), 1024 slots exactly
        int row = tid >> 4, col16 = tid & 15;
        int gr = min(m0 + row, M - 1);
        const float4* xp = (const float4*)X + (size_t)gr * 32 + col16 * 2;
        float4 v0 = xp[0], v1 = xp[1];
        float fv[8] = {v0.x, v0.y, v0.z, v0.w, v1.x, v1.y, v1.z, v1.w};
        short8 h, l;
#pragma unroll
        for (int j = 0; j < 8; ++j) {
            unsigned short hh_, ll_;
            splitf(fv[j], hh_, ll_);
            h[j] = (short)hh_;
            l[j] = (short)ll_;
        }
        As[0][col16 * 65 + row] = h;
        As[1][col16 * 65 + row] = l;
    }
    __syncthreads();

    const int isQ = wave >> 3;                  // waves 0-7: P, 8-15: Q
    const int colbase = (wave & 7) * 16;
    const unsigned short* Wh = isQ ? W2h : W1h;
    const unsigned short* Wl = isQ ? W2l : W1l;
    const float bv = isQ ? bias[colbase + l15] : 0.f;
    const int wbase = (colbase + l15) * 128 + q * 8;

    f32x4 acc[4] = {};
    short8 Bh = *(const short8*)(Wh + wbase);
    short8 Bl = *(const short8*)(Wl + wbase);

#pragma unroll 1
    for (int kt = 0; kt < 4; ++kt) {
        short8 nBh, nBl;
        if (kt < 3) {
            nBh = *(const short8*)(Wh + wbase + (kt + 1) * 32);
            nBl = *(const short8*)(Wl + wbase + (kt + 1) * 32);
        }
#pragma unroll
        for (int mt = 0; mt < 4; ++mt) {
            int ai = (kt * 4 + q) * 65 + mt * 16 + l15;
            short8 Afh = As[0][ai];
            short8 Afl = As[1][ai];
            acc[mt] = __builtin_amdgcn_mfma_f32_16x16x32_bf16(Afh, Bh, acc[mt], 0, 0, 0);
            acc[mt] = __builtin_amdgcn_mfma_f32_16x16x32_bf16(Afh, Bl, acc[mt], 0, 0, 0);
            acc[mt] = __builtin_amdgcn_mfma_f32_16x16x32_bf16(Afl, Bh, acc[mt], 0, 0, 0);
        }
        Bh = nBh; Bl = nBl;
    }

    const int col = colbase + l15;
#pragma unroll
    for (int mt = 0; mt < 4; ++mt) {
        int orow = m0 + mt * 16 + q * 4;
#pragma unroll
        for (int r = 0; r < 4; ++r) {
            int rr = orow + r;
            if (rr < M) {
                if (isQ) Q[(size_t)rr * 128 + col] = acc[mt][r] + bv;
                else P[(size_t)rr * 128 + col] = __float2half(acc[mt][r]);
            }
        }
    }
}

// deg[i] = sum over chunks (u16 hist); block emits partial sum for the scan.
__global__ __launch_bounds__(256) void deg_sum_partials(
    const unsigned short* __restrict__ hist16, int* __restrict__ deg,
    int* __restrict__ partials, int n_nodes, int nchunk) {
    __shared__ int sd[256];
    int b = blockIdx.x, t = threadIdx.x;
    int i = b * 256 + t;
    int s = 0;
    if (i < n_nodes) {
        int r = i >> RSH, ii = i & (RSZ - 1);
        const unsigned short* hp = hist16 + (size_t)r * nchunk * RSZ + ii;
        for (int c = 0; c < nchunk; ++c) s += hp[(size_t)c * RSZ];
        deg[i] = s;
    }
    sd[t] = s;
    __syncthreads();
    for (int st = 128; st > 0; st >>= 1) {
        if (t < st) sd[t] += sd[t + st];
        __syncthreads();
    }
    if (t == 0) partials[b] = sd[0];
}

// One block per 256 nodes: reduce partials locally, Hillis-Steele scan of deg,
// emit row_ptr + inv_deg, and fill base[] (per-cell exclusive offsets) in one pass.
__global__ __launch_bounds__(256) void scan_fill(
    const int* __restrict__ deg, const int* __restrict__ partials,
    const unsigned short* __restrict__ hist16, int* __restrict__ row_ptr,
    float* __restrict__ inv_deg, int* __restrict__ base,
    int n_nodes, int nchunk, int nblk) {
    __shared__ int sp[256];
    __shared__ int sd[256];
    int b = blockIdx.x, t = threadIdx.x;

    sp[t] = (t < b && t < nblk) ? partials[t] : 0;
    __syncthreads();
    for (int st = 128; st > 0; st >>= 1) {
        if (t < st) sp[t] += sp[t + st];
        __syncthreads();
    }
    int pbase = sp[0];

    int i = b * 256 + t;
    int v = (i < n_nodes) ? deg[i] : 0;
    sd[t] = v;
    __syncthreads();
    for (int d = 1; d < 256; d <<= 1) {
        int x = (t >= d) ? sd[t - d] : 0;
        __syncthreads();
        sd[t] += x;
        __syncthreads();
    }
    int excl = sd[t] - v + pbase;
    if (i < n_nodes) {
        row_ptr[i] = excl;
        int dv = v > 1 ? v : 1;
        inv_deg[i] = 1.0f / (float)dv;
        if (i == n_nodes - 1) row_ptr[n_nodes] = excl + v;
        int r = i >> RSH, ii = i & (RSZ - 1);
        int bacc = excl;
        for (int c = 0; c < nchunk; ++c) {
            size_t idx = (size_t)(r * nchunk + c) * RSZ + ii;
            base[idx] = bacc;
            bacc += hist16[idx];
        }
    }
}

// Edge-parallel, atomic-free fill: slot = base[cell] + rank[e].
__global__ __launch_bounds__(256) void fill_edges(
    const int* __restrict__ src, const int* __restrict__ dst,
    const unsigned short* __restrict__ rank, const int* __restrict__ base,
    int* __restrict__ csr, int n_edges, int nchunk) {
    int e = blockIdx.x * 256 + threadIdx.x;
    if (e >= n_edges) return;
    int d = dst[e];
    int c = e >> CSH;
    int r = d >> RSH;
    int slot = base[(size_t)(r * nchunk + c) * RSZ + (d & (RSZ - 1))] + rank[e];
    csr[slot] = src[e];
}

// ---------------- wide MFMA GEMM (layers 1,2) ----------------
template <int BN>
__global__ __launch_bounds__(2 * (BN / 16) * 64) void gemm_wide(
    const unsigned short* __restrict__ Ah, const unsigned short* __restrict__ Al,
    const unsigned short* __restrict__ W1h, const unsigned short* __restrict__ W1l,
    const unsigned short* __restrict__ W2h, const unsigned short* __restrict__ W2l,
    const float* __restrict__ bias, __half* __restrict__ P, float* __restrict__ Q, int M) {
    __shared__ short8 As[2][16 * 65];   // 33.3 KB
    constexpr int NW = BN / 16;          // waves per matrix
    constexpr int NTH = 2 * NW * 64;     // threads

    const int tid = threadIdx.x;
    const int wave = tid >> 6;
    const int lane = tid & 63;
    const int l15 = lane & 15;
    const int q = lane >> 4;
    const int m0 = blockIdx.x * 64;

#pragma unroll
    for (int it = 0; it < 2048 / NTH; ++it) {
        int s = it * NTH + tid;          // 0..2047
        int arr = s >> 10;
        int sp = s & 1023;
        int row = sp >> 4, col16 = sp & 15;
        int gr = min(m0 + row, M - 1);
        const unsigned short* src = (arr ? Al : Ah) + (size_t)gr * 128 + col16 * 8;
        As[arr][col16 * 65 + row] = *(const short8*)src;
    }
    __syncthreads();

    const int isQ = wave >= NW;
    const int colbase = (isQ ? (wave - NW) : wave) * 16;
    const unsigned short* Wh = isQ ? W2h : W1h;
    const unsigned short* Wl = isQ ? W2l : W1l;
    const float bv = isQ ? bias[colbase + l15] : 0.f;
    const int wbase = (colbase + l15) * 128 + q * 8;

    f32x4 acc[4] = {};
    short8 Bh = *(const short8*)(Wh + wbase);
    short8 Bl = *(const short8*)(Wl + wbase);

#pragma unroll 1
    for (int kt = 0; kt < 4; ++kt) {
        short8 nBh, nBl;
        if (kt < 3) {
            nBh = *(const short8*)(Wh + wbase + (kt + 1) * 32);
            nBl = *(const short8*)(Wl + wbase + (kt + 1) * 32);
        }
#pragma unroll
        for (int mt = 0; mt < 4; ++mt) {
            int ai = (kt * 4 + q) * 65 + mt * 16 + l15;
            short8 Afh = As[0][ai];
            short8 Afl = As[1][ai];
            acc[mt] = __builtin_amdgcn_mfma_f32_16x16x32_bf16(Afh, Bh, acc[mt], 0, 0, 0);
            acc[mt] = __builtin_amdgcn_mfma_f32_16x16x32_bf16(Afh, Bl, acc[mt], 0, 0, 0);
            acc[mt] = __builtin_amdgcn_mfma_f32_16x16x32_bf16(Afl, Bh, acc[mt], 0, 0, 0);
        }
        Bh = nBh; Bl = nBl;
    }

    const int col = colbase + l15;
#pragma unroll
    for (int mt = 0; mt < 4; ++mt) {
        int orow = m0 + mt * 16 + q * 4;
#pragma unroll
        for (int r = 0; r < 4; ++r) {
            int rr = orow + r;
            if (rr < M) {
                if (isQ) Q[(size_t)rr * BN + col] = acc[mt][r] + bv;
                else P[(size_t)rr * BN + col] = __float2half(acc[mt][r]);
            }
        }
    }
}

// ---------------- per-node 128-dim gather core (unified predicated rounds) ----------------
__device__ __forceinline__ void agg128_node(
    const __half* __restrict__ P, const int* __restrict__ csr,
    int beg, int end, int g, int l,
    int i0, int i1, int i2, int i3, float s[8]) {
    float a[4][8] = {};
    int e = beg;
    while (e < end) {
        int en = e + 16;
        int n0 = -1, n1 = -1, n2 = -1, n3 = -1;
        if (en < end) {
            n0 = (en + g < end) ? csr[en + g] : -1;
            n1 = (en + 4 + g < end) ? csr[en + 4 + g] : -1;
            n2 = (en + 8 + g < end) ? csr[en + 8 + g] : -1;
            n3 = (en + 12 + g < end) ? csr[en + 12 + g] : -1;
        }
        int ss[4] = {i0, i1, i2, i3};
#pragma unroll
        for (int j = 0; j < 4; ++j) {
            if (ss[j] >= 0) {
                uint4 raw = *(const uint4*)(P + (size_t)ss[j] * 128 + l * 8);
                float2 f01 = __half22float2(*reinterpret_cast<__half2*>(&raw.x));
                float2 f23 = __half22float2(*reinterpret_cast<__half2*>(&raw.y));
                float2 f45 = __half22float2(*reinterpret_cast<__half2*>(&raw.z));
                float2 f67 = __half22float2(*reinterpret_cast<__half2*>(&raw.w));
                a[j][0] += f01.x; a[j][1] += f01.y; a[j][2] += f23.x; a[j][3] += f23.y;
                a[j][4] += f45.x; a[j][5] += f45.y; a[j][6] += f67.x; a[j][7] += f67.y;
            }
        }
        e = en; i0 = n0; i1 = n1; i2 = n2; i3 = n3;
    }
#pragma unroll
    for (int k = 0; k < 8; ++k) s[k] = (a[0][k] + a[1][k]) + (a[2][k] + a[3][k]);
}

// ---------------- fused aggregation 128-dim: 2 nodes/wave, B's bootstrap prefetched ----------------
// R17: per-node start chain (row_ptr -> inv_deg -> csr idx -> gather) is the
// un-hidden latency (R15 widening was neutral; Occ 41% / VALU 44% / no pipe
// saturated). Each wave handles nodes (w, w+half); ALL node-B bootstrap loads
// (row_ptr, inv_deg, Q, round-0 indices) issue before A's gather loop -> B's
// chain hides under A's gathers. Q/inv hoisted ahead of edge loop for A too.
__global__ __launch_bounds__(256) void agg_fused128(
    const __half* __restrict__ P, const float* __restrict__ Q,
    const int* __restrict__ row_ptr, const int* __restrict__ csr,
    const float* __restrict__ inv_deg, unsigned short* __restrict__ Hh,
    unsigned short* __restrict__ Hl, int n_nodes, int half) {
    int wid = (blockIdx.x * blockDim.x + threadIdx.x) >> 6;
    int lane = threadIdx.x & 63;
    if (wid >= half) return;
    const int g = lane >> 4;    // edge slot 0..3
    const int l = lane & 15;    // 8-col group
    int nodeA = wid, nodeB = wid + half;
    bool hasB = nodeB < n_nodes;

    int begA = row_ptr[nodeA], endA = row_ptr[nodeA + 1];
    int begB = 0, endB = 0;
    if (hasB) { begB = row_ptr[nodeB]; endB = row_ptr[nodeB + 1]; }
    float wA = inv_deg[nodeA];
    float wB = hasB ? inv_deg[nodeB] : 0.f;

    // round-0 index prefetch for both nodes (predicated)
    int iA0 = (begA + g < endA) ? csr[begA + g] : -1;
    int iA1 = (begA + 4 + g < endA) ? csr[begA + 4 + g] : -1;
    int iA2 = (begA + 8 + g < endA) ? csr[begA + 8 + g] : -1;
    int iA3 = (begA + 12 + g < endA) ? csr[begA + 12 + g] : -1;
    int iB0 = (begB + g < endB) ? csr[begB + g] : -1;
    int iB1 = (begB + 4 + g < endB) ? csr[begB + 4 + g] : -1;
    int iB2 = (begB + 8 + g < endB) ? csr[begB + 8 + g] : -1;
    int iB3 = (begB + 12 + g < endB) ? csr[begB + 12 + g] : -1;

    // Q prefetch (independent of gathers)
    float4 qA0 = {}, qA1 = {}, qB0 = {}, qB1 = {};
    if (lane < 16) {
        const float4* Q4 = (const float4*)Q;
        qA0 = Q4[(size_t)nodeA * 32 + 2 * l];
        qA1 = Q4[(size_t)nodeA * 32 + 2 * l + 1];
        if (hasB) {
            qB0 = Q4[(size_t)nodeB * 32 + 2 * l];
            qB1 = Q4[(size_t)nodeB * 32 + 2 * l + 1];
        }
    }

    float sA[8], sB[8];
    agg128_node(P, csr, begA, endA, g, l, iA0, iA1, iA2, iA3, sA);
    agg128_node(P, csr, begB, endB, g, l, iB0, iB1, iB2, iB3, sB);

#pragma unroll
    for (int k = 0; k < 8; ++k) {
        sA[k] += __shfl_xor(sA[k], 16);
        sA[k] += __shfl_xor(sA[k], 32);
        sB[k] += __shfl_xor(sB[k], 16);
        sB[k] += __shfl_xor(sB[k], 32);
    }
    if (lane < 16) {
        {
            float h0 = fmaxf(fmaf(sA[0], wA, qA0.x), 0.f);
            float h1 = fmaxf(fmaf(sA[1], wA, qA0.y), 0.f);
            float h2 = fmaxf(fmaf(sA[2], wA, qA0.z), 0.f);
            float h3 = fmaxf(fmaf(sA[3], wA, qA0.w), 0.f);
            float h4 = fmaxf(fmaf(sA[4], wA, qA1.x), 0.f);
            float h5 = fmaxf(fmaf(sA[5], wA, qA1.y), 0.f);
            float h6 = fmaxf(fmaf(sA[6], wA, qA1.z), 0.f);
            float h7 = fmaxf(fmaf(sA[7], wA, qA1.w), 0.f);
            ushort4 hv0, lv0, hv1, lv1;
            splitf(h0, hv0.x, lv0.x);
            splitf(h1, hv0.y, lv0.y);
            splitf(h2, hv0.z, lv0.z);
            splitf(h3, hv0.w, lv0.w);
            splitf(h4, hv1.x, lv1.x);
            splitf(h5, hv1.y, lv1.y);
            splitf(h6, hv1.z, lv1.z);
            splitf(h7, hv1.w, lv1.w);
            ((ushort4*)Hh)[(size_t)nodeA * 32 + 2 * l] = hv0;
            ((ushort4*)Hh)[(size_t)nodeA * 32 + 2 * l + 1] = hv1;
            ((ushort4*)Hl)[(size_t)nodeA * 32 + 2 * l] = lv0;
            ((ushort4*)Hl)[(size_t)nodeA * 32 + 2 * l + 1] = lv1;
        }
        if (hasB) {
            float h0 = fmaxf(fmaf(sB[0], wB, qB0.x), 0.f);
            float h1 = fmaxf(fmaf(sB[1], wB, qB0.y), 0.f);
            float h2 = fmaxf(fmaf(sB[2], wB, qB0.z), 0.f);
            float h3 = fmaxf(fmaf(sB[3], wB, qB0.w), 0.f);
            float h4 = fmaxf(fmaf(sB[4], wB, qB1.x), 0.f);
            float h5 = fmaxf(fmaf(sB[5], wB, qB1.y), 0.f);
            float h6 = fmaxf(fmaf(sB[6], wB, qB1.z), 0.f);
            float h7 = fmaxf(fmaf(sB[7], wB, qB1.w), 0.f);
            ushort4 hv0, lv0, hv1, lv1;
            splitf(h0, hv0.x, lv0.x);
            splitf(h1, hv0.y, lv0.y);
            splitf(h2, hv0.z, lv0.z);
            splitf(h3, hv0.w, lv0.w);
            splitf(h4, hv1.x, lv1.x);
            splitf(h5, hv1.y, lv1.y);
            splitf(h6, hv1.z, lv1.z);
            splitf(h7, hv1.w, lv1.w);
            ((ushort4*)Hh)[(size_t)nodeB * 32 + 2 * l] = hv0;
            ((ushort4*)Hh)[(size_t)nodeB * 32 + 2 * l + 1] = hv1;
            ((ushort4*)Hl)[(size_t)nodeB * 32 + 2 * l] = lv0;
            ((ushort4*)Hl)[(size_t)nodeB * 32 + 2 * l + 1] = lv1;
        }
    }
}

// ---------------- per-node 64-dim gather core ----------------
__device__ __forceinline__ void agg64_node(
    const __half* __restrict__ P, const int* __restrict__ csr,
    int beg, int end, int g, int l,
    int i0, int i1, int i2, int i3, float s[4]) {
    float a[4][4] = {};
    int e = beg;
    while (e < end) {
        int en = e + 16;
        int n0 = -1, n1 = -1, n2 = -1, n3 = -1;
        if (en < end) {
            n0 = (en + g < end) ? csr[en + g] : -1;
            n1 = (en + 4 + g < end) ? csr[en + 4 + g] : -1;
            n2 = (en + 8 + g < end) ? csr[en + 8 + g] : -1;
            n3 = (en + 12 + g < end) ? csr[en + 12 + g] : -1;
        }
        int ss[4] = {i0, i1, i2, i3};
#pragma unroll
        for (int j = 0; j < 4; ++j) {
            if (ss[j] >= 0) {
                uint2 raw = *(const uint2*)(P + (size_t)ss[j] * 64 + l * 4);
                float2 f01 = __half22float2(*reinterpret_cast<__half2*>(&raw.x));
                float2 f23 = __half22float2(*reinterpret_cast<__half2*>(&raw.y));
                a[j][0] += f01.x; a[j][1] += f01.y; a[j][2] += f23.x; a[j][3] += f23.y;
            }
        }
        e = en; i0 = n0; i1 = n1; i2 = n2; i3 = n3;
    }
#pragma unroll
    for (int k = 0; k < 4; ++k) s[k] = (a[0][k] + a[1][k]) + (a[2][k] + a[3][k]);
}

// ---------------- fused aggregation 64-dim + output head: 2 nodes/wave ----------------
__global__ __launch_bounds__(256) void agg64_head(
    const __half* __restrict__ P, const float* __restrict__ Q,
    const int* __restrict__ row_ptr, const int* __restrict__ csr,
    const float* __restrict__ inv_deg, const float* __restrict__ Wo,
    const float* __restrict__ bo, float* __restrict__ out, int n_nodes, int half) {
    int wid = (blockIdx.x * blockDim.x + threadIdx.x) >> 6;
    int lane = threadIdx.x & 63;
    if (wid >= half) return;
    const int g = lane >> 4;    // edge slot 0..3
    const int l = lane & 15;    // 4-col group
    int nodeA = wid, nodeB = wid + half;
    bool hasB = nodeB < n_nodes;

    int begA = row_ptr[nodeA], endA = row_ptr[nodeA + 1];
    int begB = 0, endB = 0;
    if (hasB) { begB = row_ptr[nodeB]; endB = row_ptr[nodeB + 1]; }
    float wA = inv_deg[nodeA];
    float wB = hasB ? inv_deg[nodeB] : 0.f;

    int iA0 = (begA + g < endA) ? csr[begA + g] : -1;
    int iA1 = (begA + 4 + g < endA) ? csr[begA + 4 + g] : -1;
    int iA2 = (begA + 8 + g < endA) ? csr[begA + 8 + g] : -1;
    int iA3 = (begA + 12 + g < endA) ? csr[begA + 12 + g] : -1;
    int iB0 = (begB + g < endB) ? csr[begB + g] : -1;
    int iB1 = (begB + 4 + g < endB) ? csr[begB + 4 + g] : -1;
    int iB2 = (begB + 8 + g < endB) ? csr[begB + 8 + g] : -1;
    int iB3 = (begB + 12 + g < endB) ? csr[begB + 12 + g] : -1;

    float4 qA = {}, qB = {};
    if (lane < 16) {
        qA = ((const float4*)Q)[(size_t)nodeA * 16 + l];
        if (hasB) qB = ((const float4*)Q)[(size_t)nodeB * 16 + l];
    }

    float sA[4], sB[4];
    agg64_node(P, csr, begA, endA, g, l, iA0, iA1, iA2, iA3, sA);
    agg64_node(P, csr, begB, endB, g, l, iB0, iB1, iB2, iB3, sB);

#pragma unroll
    for (int k = 0; k < 4; ++k) {
        sA[k] += __shfl_xor(sA[k], 16);
        sA[k] += __shfl_xor(sA[k], 32);
        sB[k] += __shfl_xor(sB[k], 16);
        sB[k] += __shfl_xor(sB[k], 32);
    }
    if (lane < 16) {
        const float4* Wo4 = (const float4*)Wo;
        float4 w0 = Wo4[4 * l + 0], w1 = Wo4[4 * l + 1], w2 = Wo4[4 * l + 2], w3 = Wo4[4 * l + 3];
#pragma unroll
        for (int nsel = 0; nsel < 2; ++nsel) {
            if (nsel == 1 && !hasB) break;
            float* s = nsel ? sB : sA;
            float w = nsel ? wB : wA;
            float4 qv = nsel ? qB : qA;
            int node = nsel ? nodeB : nodeA;
            float h0 = fmaxf(fmaf(s[0], w, qv.x), 0.f);
            float h1 = fmaxf(fmaf(s[1], w, qv.y), 0.f);
            float h2 = fmaxf(fmaf(s[2], w, qv.z), 0.f);
            float h3 = fmaxf(fmaf(s[3], w, qv.w), 0.f);
            float c0 = h0 * w0.x + h1 * w1.x + h2 * w2.x + h3 * w3.x;
            float c1 = h0 * w0.y + h1 * w1.y + h2 * w2.y + h3 * w3.y;
            float c2 = h0 * w0.z + h1 * w1.z + h2 * w2.z + h3 * w3.z;
            float c3 = h0 * w0.w + h1 * w1.w + h2 * w2.w + h3 * w3.w;
#pragma unroll
            for (int m = 8; m > 0; m >>= 1) {
                c0 += __shfl_xor(c0, m);
                c1 += __shfl_xor(c1, m);
                c2 += __shfl_xor(c2, m);
                c3 += __shfl_xor(c3, m);
            }
            if (l == 0) {
                float4 r;
                r.x = c0 + bo[0];
                r.y = c1 + bo[1];
                r.z = c2 + bo[2];
                r.w = c3 + bo[3];
                ((float4*)out)[node] = r;
            }
        }
    }
}

extern "C" void kernel_launch(void* const* d_in, const int* in_sizes, int n_in,
                              void* d_out, int out_size, void* d_ws, size_t ws_size,
                              hipStream_t stream) {
    const float* x = (const float*)d_in[0];
    const int* ei = (const int*)d_in[1];
    const float* wl0 = (const float*)d_in[3];
    const float* wr0 = (const float*)d_in[4];
    const float* b0 = (const float*)d_in[5];
    const float* wl1 = (const float*)d_in[6];
    const float* wr1 = (const float*)d_in[7];
    const float* b1 = (const float*)d_in[8];
    const float* wl2 = (const float*)d_in[9];
    const float* wr2 = (const float*)d_in[10];
    const float* b2 = (const float*)d_in[11];
    const float* wo = (const float*)d_in[12];
    const float* bo = (const float*)d_in[13];

    const int n_nodes = in_sizes[0] / D;   // 50000
    const int n_edges = in_sizes[1] / 2;   // 800000
    const int* srcp = ei;
    const int* dstp = ei + n_edges;

    char* ws = (char*)d_ws;
    size_t off = 0;
    auto carve = [&](size_t bytes) -> void* {
        void* p = ws + off;
        off = (off + bytes + 255) & ~(size_t)255;
        return p;
    };
    int* deg = (int*)carve((size_t)n_nodes * 4);
    int* row_ptr = (int*)carve((size_t)(n_nodes + 1) * 4);
    int* partials = (int*)carve(256 * 4);
    float* inv_deg = (float*)carve((size_t)n_nodes * 4);
    unsigned short* rankb = (unsigned short*)carve((size_t)n_edges * 2);
    int* csr = (int*)carve((size_t)n_edges * 4);
    __half* Pbuf = (__half*)carve((size_t)n_nodes * D * 2);   // 12.8 MB
    float* Qbuf = (float*)carve((size_t)n_nodes * D * 4);     // 25.6 MB
    unsigned short* hh = (unsigned short*)carve((size_t)n_nodes * D * 2);
    unsigned short* hl = (unsigned short*)carve((size_t)n_nodes * D * 2);
    unsigned short* wt = (unsigned short*)carve((size_t)(4 * 128 * 128 + 2 * 64 * 128) * 2 * 2);
    unsigned short* wl0h = wt;
    unsigned short* wl0l = wl0h + 128 * 128;
    unsigned short* wr0h = wl0l + 128 * 128;
    unsigned short* wr0l = wr0h + 128 * 128;
    unsigned short* wl1h = wr0l + 128 * 128;
    unsigned short* wl1l = wl1h + 128 * 128;
    unsigned short* wr1h = wl1l + 128 * 128;
    unsigned short* wr1l = wr1h + 128 * 128;
    unsigned short* wl2h = wr1l + 128 * 128;
    unsigned short* wl2l = wl2h + 64 * 128;
    unsigned short* wr2h = wl2l + 64 * 128;
    unsigned short* wr2l = wr2h + 64 * 128;

    // hist/base in dedicated scratch (no P/Q aliasing; gemm_x overlaps hist)
    const int nchunk = (n_edges + CSZ - 1) >> CSH;          // 25
    unsigned* hist = (unsigned*)carve((size_t)NRANGE * nchunk * (RSZ / 2) * 4);   // 3.3 MB
    unsigned short* hist16 = (unsigned short*)hist;
    int* basep = (int*)carve((size_t)NRANGE * nchunk * RSZ * 4);                  // 6.6 MB

    const int nblk = (n_nodes + 255) / 256;                 // 196
    const int nhist = NRANGE * nchunk;                      // 100
    const int gemm_blocks = (n_nodes + 63) / 64;            // 782
    const int half = (n_nodes + 1) / 2;                     // 25000
    const int agg2_blocks = (half * 64 + 255) / 256;        // 6250

    WSplitArgs wa;
    wa.src[0] = wl0; wa.dh[0] = wl0h; wa.dl[0] = wl0l; wa.n[0] = 128;
    wa.src[1] = wr0; wa.dh[1] = wr0h; wa.dl[1] = wr0l; wa.n[1] = 128;
    wa.src[2] = wl1; wa.dh[2] = wl1h; wa.dl[2] = wl1l; wa.n[2] = 128;
    wa.src[3] = wr1; wa.dh[3] = wr1h; wa.dl[3] = wr1l; wa.n[3] = 128;
    wa.src[4] = wl2; wa.dh[4] = wl2h; wa.dl[4] = wl2l; wa.n[4] = 64;
    wa.src[5] = wr2; wa.dh[5] = wr2h; wa.dl[5] = wr2l; wa.n[5] = 64;

    // 1. split weights (tiny; gemm_x depends on W0 split)
    split_w<<<dim3(64, 6), 256, 0, stream>>>(wa);
    // 2. hist (CSR phase 1, 100 blocks) || layer-0 GEMM (782 blocks)
    hist_gemm_x<<<nhist + gemm_blocks, 1024, 0, stream>>>(
        dstp, hist, rankb, n_edges, nchunk, nhist,
        x, wl0h, wl0l, wr0h, wr0l, b0, Pbuf, Qbuf, n_nodes);
    // 3-5. rest of CSR build
    deg_sum_partials<<<nblk, 256, 0, stream>>>(hist16, deg, partials, n_nodes, nchunk);
    scan_fill<<<nblk, 256, 0, stream>>>(deg, partials, hist16, row_ptr, inv_deg, basep,
                                        n_nodes, nchunk, nblk);
    fill_edges<<<(n_edges + 255) / 256, 256, 0, stream>>>(srcp, dstp, rankb, basep, csr,
                                                          n_edges, nchunk);
    // 6-10. layers
    agg_fused128<<<agg2_blocks, 256, 0, stream>>>(
        Pbuf, Qbuf, row_ptr, csr, inv_deg, hh, hl, n_nodes, half);
    gemm_wide<128><<<gemm_blocks, 1024, 0, stream>>>(
        hh, hl, wl1h, wl1l, wr1h, wr1l, b1, Pbuf, Qbuf, n_nodes);
    agg_fused128<<<agg2_blocks, 256, 0, stream>>>(
        Pbuf, Qbuf, row_ptr, csr, inv_deg, hh, hl, n_nodes, half);
    gemm_wide<64><<<gemm_blocks, 512, 0, stream>>>(
        hh, hl, wl2h, wl2l, wr2h, wr2l, b2, Pbuf, Qbuf, n_nodes);
    agg64_head<<<agg2_blocks, 256, 0, stream>>>(
        Pbuf, Qbuf, row_ptr, csr, inv_deg, wo, bo, (float*)d_out, n_nodes, half);
}

// Round 10
// 303.574 us; speedup vs baseline: 1.4955x; 1.4955x over previous
//
#include <hip/hip_runtime.h>
#include <hip/hip_fp16.h>

#define D 128

// CSR build geometry (pow-2 so kernels use shifts, not divides)
constexpr int RSH = 14;             // log2(range size)
constexpr int RSZ = 1 << RSH;       // 16384 nodes/range
constexpr int NRANGE = 4;           // ceil(50000/16384)
constexpr int CSH = 15;             // log2(chunk edges)
constexpr int CSZ = 1 << CSH;       // 32768 edges/chunk

using short8 = __attribute__((ext_vector_type(8))) short;
using f32x4 = __attribute__((ext_vector_type(4))) float;

// split fp32 into hi/lo bf16 (truncation; residual exact in fp32)
__device__ inline void splitf(float v, unsigned short& h, unsigned short& l) {
    unsigned b = __float_as_uint(v);
    h = (unsigned short)(b >> 16);
    float fh = __uint_as_float(b & 0xffff0000u);
    float r = v - fh;
    l = (unsigned short)(__float_as_uint(r) >> 16);
}

// ---------------- weight split+transpose: W[K=128][N] -> Wt_hi/lo [N][128] ----------------
struct WSplitArgs {
    const float* src[6];
    unsigned short* dh[6];
    unsigned short* dl[6];
    int n[6];
};

__global__ __launch_bounds__(256) void split_w(WSplitArgs a) {
    int m = blockIdx.y;
    int N = a.n[m];
    int e = blockIdx.x * 256 + threadIdx.x;
    if (e >= 128 * N) return;
    int sh = (N == 128) ? 7 : 6;
    int k = e >> sh;
    int n = e & (N - 1);
    float v = a.src[m][e];
    unsigned short h, l;
    splitf(v, h, l);
    a.dh[m][n * 128 + k] = h;
    a.dl[m][n * 128 + k] = l;
}

// ---------------- layer-0 GEMM tile (device fn; 1024 threads, 16 waves) ----------------
// R18: gemm_x tiles are spread across ALL FOUR CSR-chain dispatches (hist/deg/
// scan/fill) so the deg->scan->fill segment no longer runs on an idle GPU.
__device__ __forceinline__ void gemm_x_tile(
    char* smem, int tile, const float* __restrict__ X,
    const unsigned short* __restrict__ W1h, const unsigned short* __restrict__ W1l,
    const unsigned short* __restrict__ W2h, const unsigned short* __restrict__ W2l,
    const float* __restrict__ bias, __half* __restrict__ P, float* __restrict__ Q, int M) {
    short8(*As)[16 * 65] = (short8(*)[16 * 65])smem;
    const int tid = threadIdx.x;
    const int wave = tid >> 6;          // 0..15
    const int lane = tid & 63;
    const int l15 = lane & 15;
    const int q = lane >> 4;
    const int m0 = tile * 64;

    {   // stage A tile (64 rows x 128 cols fp32 -> bf16 hi/lo), 1024 slots exactly
        int row = tid >> 4, col16 = tid & 15;
        int gr = min(m0 + row, M - 1);
        const float4* xp = (const float4*)X + (size_t)gr * 32 + col16 * 2;
        float4 v0 = xp[0], v1 = xp[1];
        float fv[8] = {v0.x, v0.y, v0.z, v0.w, v1.x, v1.y, v1.z, v1.w};
        short8 h, l;
#pragma unroll
        for (int j = 0; j < 8; ++j) {
            unsigned short hh_, ll_;
            splitf(fv[j], hh_, ll_);
            h[j] = (short)hh_;
            l[j] = (short)ll_;
        }
        As[0][col16 * 65 + row] = h;
        As[1][col16 * 65 + row] = l;
    }
    __syncthreads();

    const int isQ = wave >> 3;                  // waves 0-7: P, 8-15: Q
    const int colbase = (wave & 7) * 16;
    const unsigned short* Wh = isQ ? W2h : W1h;
    const unsigned short* Wl = isQ ? W2l : W1l;
    const float bv = isQ ? bias[colbase + l15] : 0.f;
    const int wbase = (colbase + l15) * 128 + q * 8;

    f32x4 acc[4] = {};
    short8 Bh = *(const short8*)(Wh + wbase);
    short8 Bl = *(const short8*)(Wl + wbase);

#pragma unroll 1
    for (int kt = 0; kt < 4; ++kt) {
        short8 nBh, nBl;
        if (kt < 3) {
            nBh = *(const short8*)(Wh + wbase + (kt + 1) * 32);
            nBl = *(const short8*)(Wl + wbase + (kt + 1) * 32);
        }
#pragma unroll
        for (int mt = 0; mt < 4; ++mt) {
            int ai = (kt * 4 + q) * 65 + mt * 16 + l15;
            short8 Afh = As[0][ai];
            short8 Afl = As[1][ai];
            acc[mt] = __builtin_amdgcn_mfma_f32_16x16x32_bf16(Afh, Bh, acc[mt], 0, 0, 0);
            acc[mt] = __builtin_amdgcn_mfma_f32_16x16x32_bf16(Afh, Bl, acc[mt], 0, 0, 0);
            acc[mt] = __builtin_amdgcn_mfma_f32_16x16x32_bf16(Afl, Bh, acc[mt], 0, 0, 0);
        }
        Bh = nBh; Bl = nBl;
    }

    const int col = colbase + l15;
#pragma unroll
    for (int mt = 0; mt < 4; ++mt) {
        int orow = m0 + mt * 16 + q * 4;
#pragma unroll
        for (int r = 0; r < 4; ++r) {
            int rr = orow + r;
            if (rr < M) {
                if (isQ) Q[(size_t)rr * 128 + col] = acc[mt][r] + bv;
                else P[(size_t)rr * 128 + col] = __float2half(acc[mt][r]);
            }
        }
    }
}

// ---------------- D2: hist_rank (CSR phase 1) + gemm_x tiles ----------------
__global__ __launch_bounds__(1024) void hist_gemm(
    const int* __restrict__ dst, unsigned* __restrict__ hist,
    unsigned short* __restrict__ rank, int n_edges, int nchunk, int ncsr, int tbase,
    const float* __restrict__ X,
    const unsigned short* __restrict__ W1h, const unsigned short* __restrict__ W1l,
    const unsigned short* __restrict__ W2h, const unsigned short* __restrict__ W2l,
    const float* __restrict__ bias, __half* __restrict__ P, float* __restrict__ Q, int M) {
    __shared__ __align__(16) char smem[2 * 16 * 65 * 16];   // 33280 B (hist needs 32768)
    const int b = blockIdx.x;
    const int tid = threadIdx.x;

    if (b < ncsr) {
        unsigned* lh = (unsigned*)smem;   // RSZ/2 = 8192 words of packed u16 counts
        int r = b & (NRANGE - 1), c = b >> 2;
        for (int i = tid; i < RSZ / 2; i += 1024) lh[i] = 0;
        __syncthreads();
        int e0 = c << CSH, e1 = min(n_edges, e0 + CSZ);
        for (int e = e0 + tid; e < e1; e += 1024) {
            int d = dst[e];
            if ((d >> RSH) == r) {
                int ii = d & (RSZ - 1);
                unsigned sh = (ii & 1) * 16;
                unsigned old = atomicAdd(&lh[ii >> 1], 1u << sh);
                rank[e] = (unsigned short)((old >> sh) & 0xffffu);
            }
        }
        __syncthreads();
        unsigned* gh = hist + (size_t)(r * nchunk + c) * (RSZ / 2);
        for (int i = tid; i < RSZ / 2; i += 1024) gh[i] = lh[i];
        return;
    }
    gemm_x_tile(smem, tbase + b - ncsr, X, W1h, W1l, W2h, W2l, bias, P, Q, M);
}

// ---------------- D3: deg_sum_partials (1024-thr) + gemm_x tiles ----------------
__global__ __launch_bounds__(1024) void deg_gemm(
    const unsigned short* __restrict__ hist16, int* __restrict__ deg,
    int* __restrict__ partials, int n_nodes, int nchunk, int ncsr, int tbase,
    const float* __restrict__ X,
    const unsigned short* __restrict__ W1h, const unsigned short* __restrict__ W1l,
    const unsigned short* __restrict__ W2h, const unsigned short* __restrict__ W2l,
    const float* __restrict__ bias, __half* __restrict__ P, float* __restrict__ Q, int M) {
    __shared__ __align__(16) char smem[2 * 16 * 65 * 16];
    const int b = blockIdx.x;
    const int t = threadIdx.x;

    if (b < ncsr) {
        int* sd = (int*)smem;            // 1024 ints
        int i = b * 1024 + t;
        int s = 0;
        if (i < n_nodes) {
            int r = i >> RSH, ii = i & (RSZ - 1);
            const unsigned short* hp = hist16 + (size_t)r * nchunk * RSZ + ii;
            for (int c = 0; c < nchunk; ++c) s += hp[(size_t)c * RSZ];
            deg[i] = s;
        }
        sd[t] = s;
        __syncthreads();
        for (int st = 512; st > 0; st >>= 1) {
            if (t < st) sd[t] += sd[t + st];
            __syncthreads();
        }
        if (t == 0) partials[b] = sd[0];
        return;
    }
    gemm_x_tile(smem, tbase + b - ncsr, X, W1h, W1l, W2h, W2l, bias, P, Q, M);
}

// ---------------- D4: scan_fill (1024-thr) + gemm_x tiles ----------------
__global__ __launch_bounds__(1024) void scan_gemm(
    const int* __restrict__ deg, const int* __restrict__ partials,
    const unsigned short* __restrict__ hist16, int* __restrict__ row_ptr,
    float* __restrict__ inv_deg, int* __restrict__ base,
    int n_nodes, int nchunk, int nblk, int ncsr, int tbase,
    const float* __restrict__ X,
    const unsigned short* __restrict__ W1h, const unsigned short* __restrict__ W1l,
    const unsigned short* __restrict__ W2h, const unsigned short* __restrict__ W2l,
    const float* __restrict__ bias, __half* __restrict__ P, float* __restrict__ Q, int M) {
    __shared__ __align__(16) char smem[2 * 16 * 65 * 16];
    const int b = blockIdx.x;
    const int t = threadIdx.x;

    if (b < ncsr) {
        int* sp = (int*)smem;            // 1024 ints
        int* sd = sp + 1024;             // 1024 ints (8 KB total, fits union)

        sp[t] = (t < b && t < nblk) ? partials[t] : 0;
        __syncthreads();
        for (int st = 512; st > 0; st >>= 1) {
            if (t < st) sp[t] += sp[t + st];
            __syncthreads();
        }
        int pbase = sp[0];

        int i = b * 1024 + t;
        int v = (i < n_nodes) ? deg[i] : 0;
        sd[t] = v;
        __syncthreads();
        for (int d = 1; d < 1024; d <<= 1) {
            int x = (t >= d) ? sd[t - d] : 0;
            __syncthreads();
            sd[t] += x;
            __syncthreads();
        }
        int excl = sd[t] - v + pbase;
        if (i < n_nodes) {
            row_ptr[i] = excl;
            int dv = v > 1 ? v : 1;
            inv_deg[i] = 1.0f / (float)dv;
            if (i == n_nodes - 1) row_ptr[n_nodes] = excl + v;
            int r = i >> RSH, ii = i & (RSZ - 1);
            int bacc = excl;
            for (int c = 0; c < nchunk; ++c) {
                size_t idx = (size_t)(r * nchunk + c) * RSZ + ii;
                base[idx] = bacc;
                bacc += hist16[idx];
            }
        }
        return;
    }
    gemm_x_tile(smem, tbase + b - ncsr, X, W1h, W1l, W2h, W2l, bias, P, Q, M);
}

// ---------------- D5: fill_edges (1024-thr) + gemm_x tiles ----------------
__global__ __launch_bounds__(1024) void fill_gemm(
    const int* __restrict__ src, const int* __restrict__ dst,
    const unsigned short* __restrict__ rank, const int* __restrict__ base,
    int* __restrict__ csr, int n_edges, int nchunk, int ncsr, int tbase,
    const float* __restrict__ X,
    const unsigned short* __restrict__ W1h, const unsigned short* __restrict__ W1l,
    const unsigned short* __restrict__ W2h, const unsigned short* __restrict__ W2l,
    const float* __restrict__ bias, __half* __restrict__ P, float* __restrict__ Q, int M) {
    __shared__ __align__(16) char smem[2 * 16 * 65 * 16];
    const int b = blockIdx.x;
    const int t = threadIdx.x;

    if (b < ncsr) {
        int e = b * 1024 + t;
        if (e < n_edges) {
            int d = dst[e];
            int c = e >> CSH;
            int r = d >> RSH;
            int slot = base[(size_t)(r * nchunk + c) * RSZ + (d & (RSZ - 1))] + rank[e];
            csr[slot] = src[e];
        }
        return;
    }
    gemm_x_tile(smem, tbase + b - ncsr, X, W1h, W1l, W2h, W2l, bias, P, Q, M);
}

// ---------------- wide MFMA GEMM (layers 1,2) -- R16 measured ----------------
template <int BN>
__global__ __launch_bounds__(2 * (BN / 16) * 64) void gemm_wide(
    const unsigned short* __restrict__ Ah, const unsigned short* __restrict__ Al,
    const unsigned short* __restrict__ W1h, const unsigned short* __restrict__ W1l,
    const unsigned short* __restrict__ W2h, const unsigned short* __restrict__ W2l,
    const float* __restrict__ bias, __half* __restrict__ P, float* __restrict__ Q, int M) {
    __shared__ short8 As[2][16 * 65];   // 33.3 KB
    constexpr int NW = BN / 16;          // waves per matrix
    constexpr int NTH = 2 * NW * 64;     // threads

    const int tid = threadIdx.x;
    const int wave = tid >> 6;
    const int lane = tid & 63;
    const int l15 = lane & 15;
    const int q = lane >> 4;
    const int m0 = blockIdx.x * 64;

#pragma unroll
    for (int it = 0; it < 2048 / NTH; ++it) {
        int s = it * NTH + tid;          // 0..2047
        int arr = s >> 10;
        int sp = s & 1023;
        int row = sp >> 4, col16 = sp & 15;
        int gr = min(m0 + row, M - 1);
        const unsigned short* src = (arr ? Al : Ah) + (size_t)gr * 128 + col16 * 8;
        As[arr][col16 * 65 + row] = *(const short8*)src;
    }
    __syncthreads();

    const int isQ = wave >= NW;
    const int colbase = (isQ ? (wave - NW) : wave) * 16;
    const unsigned short* Wh = isQ ? W2h : W1h;
    const unsigned short* Wl = isQ ? W2l : W1l;
    const float bv = isQ ? bias[colbase + l15] : 0.f;
    const int wbase = (colbase + l15) * 128 + q * 8;

    f32x4 acc[4] = {};
    short8 Bh = *(const short8*)(Wh + wbase);
    short8 Bl = *(const short8*)(Wl + wbase);

#pragma unroll 1
    for (int kt = 0; kt < 4; ++kt) {
        short8 nBh, nBl;
        if (kt < 3) {
            nBh = *(const short8*)(Wh + wbase + (kt + 1) * 32);
            nBl = *(const short8*)(Wl + wbase + (kt + 1) * 32);
        }
#pragma unroll
        for (int mt = 0; mt < 4; ++mt) {
            int ai = (kt * 4 + q) * 65 + mt * 16 + l15;
            short8 Afh = As[0][ai];
            short8 Afl = As[1][ai];
            acc[mt] = __builtin_amdgcn_mfma_f32_16x16x32_bf16(Afh, Bh, acc[mt], 0, 0, 0);
            acc[mt] = __builtin_amdgcn_mfma_f32_16x16x32_bf16(Afh, Bl, acc[mt], 0, 0, 0);
            acc[mt] = __builtin_amdgcn_mfma_f32_16x16x32_bf16(Afl, Bh, acc[mt], 0, 0, 0);
        }
        Bh = nBh; Bl = nBl;
    }

    const int col = colbase + l15;
#pragma unroll
    for (int mt = 0; mt < 4; ++mt) {
        int orow = m0 + mt * 16 + q * 4;
#pragma unroll
        for (int r = 0; r < 4; ++r) {
            int rr = orow + r;
            if (rr < M) {
                if (isQ) Q[(size_t)rr * BN + col] = acc[mt][r] + bv;
                else P[(size_t)rr * BN + col] = __float2half(acc[mt][r]);
            }
        }
    }
}

// ---------------- fused aggregation 128-dim (R16 measured: 42.4us, Occ 41%) ----------------
// One node per wave; 16-edge rounds, 4 independent gathers in flight. R17's
// 2-node variant REVERTED: VGPR 44->120 halved occupancy -> in-flight request
// concurrency (the actual limiter) dropped; beyond-L2 BW fell 2.87->1.08 TB/s.
__global__ __launch_bounds__(256) void agg_fused128(
    const __half* __restrict__ P, const float* __restrict__ Q,
    const int* __restrict__ row_ptr, const int* __restrict__ csr,
    const float* __restrict__ inv_deg, unsigned short* __restrict__ Hh,
    unsigned short* __restrict__ Hl, int n_nodes) {
    int node = (blockIdx.x * blockDim.x + threadIdx.x) >> 6;
    int lane = threadIdx.x & 63;
    if (node >= n_nodes) return;
    int beg = row_ptr[node], end = row_ptr[node + 1];
    const int g = lane >> 4;    // edge slot 0..3
    const int l = lane & 15;    // 8-col group
    float a[4][8] = {};         // 4 independent accumulator banks
    int e = beg;
    bool have = (e + 16 <= end);
    int i0 = 0, i1 = 0, i2 = 0, i3 = 0;
    if (have) { i0 = csr[e + g]; i1 = csr[e + 4 + g]; i2 = csr[e + 8 + g]; i3 = csr[e + 12 + g]; }
    while (have) {
        int en = e + 16;
        bool hn = (en + 16 <= end);
        int n0 = 0, n1 = 0, n2 = 0, n3 = 0;
        if (hn) { n0 = csr[en + g]; n1 = csr[en + 4 + g]; n2 = csr[en + 8 + g]; n3 = csr[en + 12 + g]; }
        int ss[4] = {i0, i1, i2, i3};
#pragma unroll
        for (int j = 0; j < 4; ++j) {
            uint4 raw = *(const uint4*)(P + (size_t)ss[j] * 128 + l * 8);
            float2 f01 = __half22float2(*reinterpret_cast<__half2*>(&raw.x));
            float2 f23 = __half22float2(*reinterpret_cast<__half2*>(&raw.y));
            float2 f45 = __half22float2(*reinterpret_cast<__half2*>(&raw.z));
            float2 f67 = __half22float2(*reinterpret_cast<__half2*>(&raw.w));
            a[j][0] += f01.x; a[j][1] += f01.y; a[j][2] += f23.x; a[j][3] += f23.y;
            a[j][4] += f45.x; a[j][5] += f45.y; a[j][6] += f67.x; a[j][7] += f67.y;
        }
        e = en; i0 = n0; i1 = n1; i2 = n2; i3 = n3; have = hn;
    }
    if (e < end) {
        int p0 = e + g, p1 = e + 4 + g, p2 = e + 8 + g, p3 = e + 12 + g;
        int j0 = (p0 < end) ? csr[p0] : -1;
        int j1 = (p1 < end) ? csr[p1] : -1;
        int j2 = (p2 < end) ? csr[p2] : -1;
        int j3 = (p3 < end) ? csr[p3] : -1;
        int ss[4] = {j0, j1, j2, j3};
#pragma unroll
        for (int j = 0; j < 4; ++j) {
            if (ss[j] >= 0) {
                uint4 raw = *(const uint4*)(P + (size_t)ss[j] * 128 + l * 8);
                float2 f01 = __half22float2(*reinterpret_cast<__half2*>(&raw.x));
                float2 f23 = __half22float2(*reinterpret_cast<__half2*>(&raw.y));
                float2 f45 = __half22float2(*reinterpret_cast<__half2*>(&raw.z));
                float2 f67 = __half22float2(*reinterpret_cast<__half2*>(&raw.w));
                a[j][0] += f01.x; a[j][1] += f01.y; a[j][2] += f23.x; a[j][3] += f23.y;
                a[j][4] += f45.x; a[j][5] += f45.y; a[j][6] += f67.x; a[j][7] += f67.y;
            }
        }
    }
    float s[8];
#pragma unroll
    for (int k = 0; k < 8; ++k) {
        s[k] = (a[0][k] + a[1][k]) + (a[2][k] + a[3][k]);
        s[k] += __shfl_xor(s[k], 16);
        s[k] += __shfl_xor(s[k], 32);
    }
    if (lane < 16) {
        float w = inv_deg[node];
        const float4* Q4 = (const float4*)Q;
        float4 q0 = Q4[(size_t)node * 32 + 2 * l];
        float4 q1 = Q4[(size_t)node * 32 + 2 * l + 1];
        float h0 = fmaxf(fmaf(s[0], w, q0.x), 0.f);
        float h1 = fmaxf(fmaf(s[1], w, q0.y), 0.f);
        float h2 = fmaxf(fmaf(s[2], w, q0.z), 0.f);
        float h3 = fmaxf(fmaf(s[3], w, q0.w), 0.f);
        float h4 = fmaxf(fmaf(s[4], w, q1.x), 0.f);
        float h5 = fmaxf(fmaf(s[5], w, q1.y), 0.f);
        float h6 = fmaxf(fmaf(s[6], w, q1.z), 0.f);
        float h7 = fmaxf(fmaf(s[7], w, q1.w), 0.f);
        ushort4 hv0, lv0, hv1, lv1;
        splitf(h0, hv0.x, lv0.x);
        splitf(h1, hv0.y, lv0.y);
        splitf(h2, hv0.z, lv0.z);
        splitf(h3, hv0.w, lv0.w);
        splitf(h4, hv1.x, lv1.x);
        splitf(h5, hv1.y, lv1.y);
        splitf(h6, hv1.z, lv1.z);
        splitf(h7, hv1.w, lv1.w);
        ((ushort4*)Hh)[(size_t)node * 32 + 2 * l] = hv0;
        ((ushort4*)Hh)[(size_t)node * 32 + 2 * l + 1] = hv1;
        ((ushort4*)Hl)[(size_t)node * 32 + 2 * l] = lv0;
        ((ushort4*)Hl)[(size_t)node * 32 + 2 * l + 1] = lv1;
    }
}

// ---------------- fused aggregation 64-dim (fp16 gather) + output head ----------------
__global__ __launch_bounds__(256) void agg64_head(
    const __half* __restrict__ P, const float* __restrict__ Q,
    const int* __restrict__ row_ptr, const int* __restrict__ csr,
    const float* __restrict__ inv_deg, const float* __restrict__ Wo,
    const float* __restrict__ bo, float* __restrict__ out, int n_nodes) {
    int node = (blockIdx.x * blockDim.x + threadIdx.x) >> 6;
    int lane = threadIdx.x & 63;
    if (node >= n_nodes) return;
    int beg = row_ptr[node], end = row_ptr[node + 1];
    const int g = lane >> 4;    // edge slot 0..3
    const int l = lane & 15;    // 4-col group
    float a[4][4] = {};
    int e = beg;
    bool have = (e + 16 <= end);
    int i0 = 0, i1 = 0, i2 = 0, i3 = 0;
    if (have) { i0 = csr[e + g]; i1 = csr[e + 4 + g]; i2 = csr[e + 8 + g]; i3 = csr[e + 12 + g]; }
    while (have) {
        int en = e + 16;
        bool hn = (en + 16 <= end);
        int n0 = 0, n1 = 0, n2 = 0, n3 = 0;
        if (hn) { n0 = csr[en + g]; n1 = csr[en + 4 + g]; n2 = csr[en + 8 + g]; n3 = csr[en + 12 + g]; }
        int ss[4] = {i0, i1, i2, i3};
#pragma unroll
        for (int j = 0; j < 4; ++j) {
            uint2 raw = *(const uint2*)(P + (size_t)ss[j] * 64 + l * 4);
            float2 f01 = __half22float2(*reinterpret_cast<__half2*>(&raw.x));
            float2 f23 = __half22float2(*reinterpret_cast<__half2*>(&raw.y));
            a[j][0] += f01.x; a[j][1] += f01.y; a[j][2] += f23.x; a[j][3] += f23.y;
        }
        e = en; i0 = n0; i1 = n1; i2 = n2; i3 = n3; have = hn;
    }
    if (e < end) {
        int p0 = e + g, p1 = e + 4 + g, p2 = e + 8 + g, p3 = e + 12 + g;
        int j0 = (p0 < end) ? csr[p0] : -1;
        int j1 = (p1 < end) ? csr[p1] : -1;
        int j2 = (p2 < end) ? csr[p2] : -1;
        int j3 = (p3 < end) ? csr[p3] : -1;
        int ss[4] = {j0, j1, j2, j3};
#pragma unroll
        for (int j = 0; j < 4; ++j) {
            if (ss[j] >= 0) {
                uint2 raw = *(const uint2*)(P + (size_t)ss[j] * 64 + l * 4);
                float2 f01 = __half22float2(*reinterpret_cast<__half2*>(&raw.x));
                float2 f23 = __half22float2(*reinterpret_cast<__half2*>(&raw.y));
                a[j][0] += f01.x; a[j][1] += f01.y; a[j][2] += f23.x; a[j][3] += f23.y;
            }
        }
    }
    float s0 = (a[0][0] + a[1][0]) + (a[2][0] + a[3][0]);
    float s1 = (a[0][1] + a[1][1]) + (a[2][1] + a[3][1]);
    float s2 = (a[0][2] + a[1][2]) + (a[2][2] + a[3][2]);
    float s3 = (a[0][3] + a[1][3]) + (a[2][3] + a[3][3]);
    s0 += __shfl_xor(s0, 16); s0 += __shfl_xor(s0, 32);
    s1 += __shfl_xor(s1, 16); s1 += __shfl_xor(s1, 32);
    s2 += __shfl_xor(s2, 16); s2 += __shfl_xor(s2, 32);
    s3 += __shfl_xor(s3, 16); s3 += __shfl_xor(s3, 32);
    if (lane < 16) {
        float w = inv_deg[node];
        float4 qv = ((const float4*)Q)[(size_t)node * 16 + l];
        float h0 = fmaxf(fmaf(s0, w, qv.x), 0.f);
        float h1 = fmaxf(fmaf(s1, w, qv.y), 0.f);
        float h2 = fmaxf(fmaf(s2, w, qv.z), 0.f);
        float h3 = fmaxf(fmaf(s3, w, qv.w), 0.f);
        const float4* Wo4 = (const float4*)Wo;
        float4 w0 = Wo4[4 * l + 0], w1 = Wo4[4 * l + 1], w2 = Wo4[4 * l + 2], w3 = Wo4[4 * l + 3];
        float c0 = h0 * w0.x + h1 * w1.x + h2 * w2.x + h3 * w3.x;
        float c1 = h0 * w0.y + h1 * w1.y + h2 * w2.y + h3 * w3.y;
        float c2 = h0 * w0.z + h1 * w1.z + h2 * w2.z + h3 * w3.z;
        float c3 = h0 * w0.w + h1 * w1.w + h2 * w2.w + h3 * w3.w;
#pragma unroll
        for (int m = 8; m > 0; m >>= 1) {
            c0 += __shfl_xor(c0, m);
            c1 += __shfl_xor(c1, m);
            c2 += __shfl_xor(c2, m);
            c3 += __shfl_xor(c3, m);
        }
        if (l == 0) {
            float4 r;
            r.x = c0 + bo[0];
            r.y = c1 + bo[1];
            r.z = c2 + bo[2];
            r.w = c3 + bo[3];
            ((float4*)out)[node] = r;
        }
    }
}

extern "C" void kernel_launch(void* const* d_in, const int* in_sizes, int n_in,
                              void* d_out, int out_size, void* d_ws, size_t ws_size,
                              hipStream_t stream) {
    const float* x = (const float*)d_in[0];
    const int* ei = (const int*)d_in[1];
    const float* wl0 = (const float*)d_in[3];
    const float* wr0 = (const float*)d_in[4];
    const float* b0 = (const float*)d_in[5];
    const float* wl1 = (const float*)d_in[6];
    const float* wr1 = (const float*)d_in[7];
    const float* b1 = (const float*)d_in[8];
    const float* wl2 = (const float*)d_in[9];
    const float* wr2 = (const float*)d_in[10];
    const float* b2 = (const float*)d_in[11];
    const float* wo = (const float*)d_in[12];
    const float* bo = (const float*)d_in[13];

    const int n_nodes = in_sizes[0] / D;   // 50000
    const int n_edges = in_sizes[1] / 2;   // 800000
    const int* srcp = ei;
    const int* dstp = ei + n_edges;

    char* ws = (char*)d_ws;
    size_t off = 0;
    auto carve = [&](size_t bytes) -> void* {
        void* p = ws + off;
        off = (off + bytes + 255) & ~(size_t)255;
        return p;
    };
    int* deg = (int*)carve((size_t)n_nodes * 4);
    int* row_ptr = (int*)carve((size_t)(n_nodes + 1) * 4);
    int* partials = (int*)carve(256 * 4);
    float* inv_deg = (float*)carve((size_t)n_nodes * 4);
    unsigned short* rankb = (unsigned short*)carve((size_t)n_edges * 2);
    int* csr = (int*)carve((size_t)n_edges * 4);
    __half* Pbuf = (__half*)carve((size_t)n_nodes * D * 2);   // 12.8 MB
    float* Qbuf = (float*)carve((size_t)n_nodes * D * 4);     // 25.6 MB
    unsigned short* hh = (unsigned short*)carve((size_t)n_nodes * D * 2);
    unsigned short* hl = (unsigned short*)carve((size_t)n_nodes * D * 2);
    unsigned short* wt = (unsigned short*)carve((size_t)(4 * 128 * 128 + 2 * 64 * 128) * 2 * 2);
    unsigned short* wl0h = wt;
    unsigned short* wl0l = wl0h + 128 * 128;
    unsigned short* wr0h = wl0l + 128 * 128;
    unsigned short* wr0l = wr0h + 128 * 128;
    unsigned short* wl1h = wr0l + 128 * 128;
    unsigned short* wl1l = wl1h + 128 * 128;
    unsigned short* wr1h = wl1l + 128 * 128;
    unsigned short* wr1l = wr1h + 128 * 128;
    unsigned short* wl2h = wr1l + 128 * 128;
    unsigned short* wl2l = wl2h + 64 * 128;
    unsigned short* wr2h = wl2l + 64 * 128;
    unsigned short* wr2l = wr2h + 64 * 128;

    // hist/base in dedicated scratch (no P/Q aliasing; gemm_x overlaps CSR chain)
    const int nchunk = (n_edges + CSZ - 1) >> CSH;          // 25
    unsigned* hist = (unsigned*)carve((size_t)NRANGE * nchunk * (RSZ / 2) * 4);   // 3.3 MB
    unsigned short* hist16 = (unsigned short*)hist;
    int* basep = (int*)carve((size_t)NRANGE * nchunk * RSZ * 4);                  // 6.6 MB

    const int nhist = NRANGE * nchunk;                      // 100
    const int ndeg = (n_nodes + 1023) / 1024;               // 49
    const int nfill = (n_edges + 1023) / 1024;              // 782
    const int gemm_blocks = (n_nodes + 63) / 64;            // 782 tiles total
    const int agg_blocks = (n_nodes * 64 + 255) / 256;

    // gemm_x tile distribution across the 4 CSR-chain dispatches
    const int t1 = 250, t2 = 250, t3 = 250;
    const int t4 = gemm_blocks - t1 - t2 - t3;              // 32

    WSplitArgs wa;
    wa.src[0] = wl0; wa.dh[0] = wl0h; wa.dl[0] = wl0l; wa.n[0] = 128;
    wa.src[1] = wr0; wa.dh[1] = wr0h; wa.dl[1] = wr0l; wa.n[1] = 128;
    wa.src[2] = wl1; wa.dh[2] = wl1h; wa.dl[2] = wl1l; wa.n[2] = 128;
    wa.src[3] = wr1; wa.dh[3] = wr1h; wa.dl[3] = wr1l; wa.n[3] = 128;
    wa.src[4] = wl2; wa.dh[4] = wl2h; wa.dl[4] = wl2l; wa.n[4] = 64;
    wa.src[5] = wr2; wa.dh[5] = wr2h; wa.dl[5] = wr2l; wa.n[5] = 64;

    // 1. split weights (tiny; gemm_x tiles depend on W0 split)
    split_w<<<dim3(64, 6), 256, 0, stream>>>(wa);
    // 2-5. CSR chain, each dispatch carrying a slice of gemm_x tiles
    hist_gemm<<<nhist + t1, 1024, 0, stream>>>(
        dstp, hist, rankb, n_edges, nchunk, nhist, 0,
        x, wl0h, wl0l, wr0h, wr0l, b0, Pbuf, Qbuf, n_nodes);
    deg_gemm<<<ndeg + t2, 1024, 0, stream>>>(
        hist16, deg, partials, n_nodes, nchunk, ndeg, t1,
        x, wl0h, wl0l, wr0h, wr0l, b0, Pbuf, Qbuf, n_nodes);
    scan_gemm<<<ndeg + t3, 1024, 0, stream>>>(
        deg, partials, hist16, row_ptr, inv_deg, basep, n_nodes, nchunk, ndeg,
        ndeg, t1 + t2,
        x, wl0h, wl0l, wr0h, wr0l, b0, Pbuf, Qbuf, n_nodes);
    fill_gemm<<<nfill + t4, 1024, 0, stream>>>(
        srcp, dstp, rankb, basep, csr, n_edges, nchunk, nfill, t1 + t2 + t3,
        x, wl0h, wl0l, wr0h, wr0l, b0, Pbuf, Qbuf, n_nodes);
    // 6-10. layers
    agg_fused128<<<agg_blocks, 256, 0, stream>>>(Pbuf, Qbuf, row_ptr, csr, inv_deg, hh, hl, n_nodes);
    gemm_wide<128><<<gemm_blocks, 1024, 0, stream>>>(
        hh, hl, wl1h, wl1l, wr1h, wr1l, b1, Pbuf, Qbuf, n_nodes);
    agg_fused128<<<agg_blocks, 256, 0, stream>>>(Pbuf, Qbuf, row_ptr, csr, inv_deg, hh, hl, n_nodes);
    gemm_wide<64><<<gemm_blocks, 512, 0, stream>>>(
        hh, hl, wl2h, wl2l, wr2h, wr2l, b2, Pbuf, Qbuf, n_nodes);
    agg64_head<<<agg_blocks, 256, 0, stream>>>(Pbuf, Qbuf, row_ptr, csr, inv_deg,
                                               wo, bo, (float*)d_out, n_nodes);
}

// Round 11
// 289.314 us; speedup vs baseline: 1.5693x; 1.0493x over previous
//
#include <hip/hip_runtime.h>
#include <hip/hip_fp16.h>

#define D 128

// CSR build geometry (pow-2 so kernels use shifts, not divides)
constexpr int RSH = 14;             // log2(range size)
constexpr int RSZ = 1 << RSH;       // 16384 nodes/range
constexpr int NRANGE = 4;           // ceil(50000/16384)
constexpr int CSH = 15;             // log2(chunk edges)
constexpr int CSZ = 1 << CSH;       // 32768 edges/chunk

using short8 = __attribute__((ext_vector_type(8))) short;
using f32x4 = __attribute__((ext_vector_type(4))) float;

// split fp32 into hi/lo bf16 (truncation; residual exact in fp32)
__device__ inline void splitf(float v, unsigned short& h, unsigned short& l) {
    unsigned b = __float_as_uint(v);
    h = (unsigned short)(b >> 16);
    float fh = __uint_as_float(b & 0xffff0000u);
    float r = v - fh;
    l = (unsigned short)(__float_as_uint(r) >> 16);
}

// ---------------- weight split+transpose: W[K=128][N] -> Wt_hi/lo [N][128] ----------------
struct WSplitArgs {
    const float* src[6];
    unsigned short* dh[6];
    unsigned short* dl[6];
    int n[6];
};

__global__ __launch_bounds__(256) void split_w(WSplitArgs a) {
    int m = blockIdx.y;
    int N = a.n[m];
    int e = blockIdx.x * 256 + threadIdx.x;
    if (e >= 128 * N) return;
    int sh = (N == 128) ? 7 : 6;
    int k = e >> sh;
    int n = e & (N - 1);
    float v = a.src[m][e];
    unsigned short h, l;
    splitf(v, h, l);
    a.dh[m][n * 128 + k] = h;
    a.dl[m][n * 128 + k] = l;
}

// ---------------- fused hist_rank (CSR phase 1) + layer-0 GEMM ----------------
// Blocks [0,nhist): hist; rest: gemm tiles (fills idle CUs during hist).
__global__ __launch_bounds__(1024) void hist_gemm_x(
    const int* __restrict__ dst, unsigned* __restrict__ hist,
    unsigned short* __restrict__ rank, int n_edges, int nchunk, int nhist,
    const float* __restrict__ X,
    const unsigned short* __restrict__ W1h, const unsigned short* __restrict__ W1l,
    const unsigned short* __restrict__ W2h, const unsigned short* __restrict__ W2l,
    const float* __restrict__ bias, __half* __restrict__ P, float* __restrict__ Q, int M) {
    __shared__ __align__(16) char smem[2 * 16 * 65 * 16];   // 33280 B (hist needs 32768)

    const int b = blockIdx.x;
    const int tid = threadIdx.x;

    if (b < nhist) {
        // ---- hist_rank path ----
        unsigned* lh = (unsigned*)smem;   // RSZ/2 = 8192 words of packed u16 counts
        int r = b & (NRANGE - 1), c = b >> 2;
        for (int i = tid; i < RSZ / 2; i += 1024) lh[i] = 0;
        __syncthreads();
        int e0 = c << CSH, e1 = min(n_edges, e0 + CSZ);
        for (int e = e0 + tid; e < e1; e += 1024) {
            int d = dst[e];
            if ((d >> RSH) == r) {
                int ii = d & (RSZ - 1);
                unsigned sh = (ii & 1) * 16;
                unsigned old = atomicAdd(&lh[ii >> 1], 1u << sh);
                rank[e] = (unsigned short)((old >> sh) & 0xffffu);
            }
        }
        __syncthreads();
        unsigned* gh = hist + (size_t)(r * nchunk + c) * (RSZ / 2);
        for (int i = tid; i < RSZ / 2; i += 1024) gh[i] = lh[i];
        return;
    }

    // ---- gemm_x path ----
    short8(*As)[16 * 65] = (short8(*)[16 * 65])smem;
    const int wave = tid >> 6;          // 0..15
    const int lane = tid & 63;
    const int l15 = lane & 15;
    const int q = lane >> 4;
    const int m0 = (b - nhist) * 64;

    {   // stage A tile (64 rows x 128 cols fp32 -> bf16 hi/lo), 1024 slots exactly
        int row = tid >> 4, col16 = tid & 15;
        int gr = min(m0 + row, M - 1);
        const float4* xp = (const float4*)X + (size_t)gr * 32 + col16 * 2;
        float4 v0 = xp[0], v1 = xp[1];
        float fv[8] = {v0.x, v0.y, v0.z, v0.w, v1.x, v1.y, v1.z, v1.w};
        short8 h, l;
#pragma unroll
        for (int j = 0; j < 8; ++j) {
            unsigned short hh_, ll_;
            splitf(fv[j], hh_, ll_);
            h[j] = (short)hh_;
            l[j] = (short)ll_;
        }
        As[0][col16 * 65 + row] = h;
        As[1][col16 * 65 + row] = l;
    }
    __syncthreads();

    const int isQ = wave >> 3;                  // waves 0-7: P, 8-15: Q
    const int colbase = (wave & 7) * 16;
    const unsigned short* Wh = isQ ? W2h : W1h;
    const unsigned short* Wl = isQ ? W2l : W1l;
    const float bv = isQ ? bias[colbase + l15] : 0.f;

    f32x4 acc[4] = {};

#pragma unroll 1
    for (int kt = 0; kt < 4; ++kt) {
        int c = colbase + l15;
        int woff = c * 128 + kt * 32 + q * 8;
        short8 Bh = *(const short8*)(Wh + woff);
        short8 Bl = *(const short8*)(Wl + woff);
#pragma unroll
        for (int mt = 0; mt < 4; ++mt) {
            int ai = (kt * 4 + q) * 65 + mt * 16 + l15;
            short8 Afh = As[0][ai];
            short8 Afl = As[1][ai];
            acc[mt] = __builtin_amdgcn_mfma_f32_16x16x32_bf16(Afh, Bh, acc[mt], 0, 0, 0);
            acc[mt] = __builtin_amdgcn_mfma_f32_16x16x32_bf16(Afh, Bl, acc[mt], 0, 0, 0);
            acc[mt] = __builtin_amdgcn_mfma_f32_16x16x32_bf16(Afl, Bh, acc[mt], 0, 0, 0);
        }
    }

    const int col = colbase + l15;
#pragma unroll
    for (int mt = 0; mt < 4; ++mt) {
        int orow = m0 + mt * 16 + q * 4;
#pragma unroll
        for (int r = 0; r < 4; ++r) {
            int rr = orow + r;
            if (rr < M) {
                if (isQ) Q[(size_t)rr * 128 + col] = acc[mt][r] + bv;
                else P[(size_t)rr * 128 + col] = __float2half(acc[mt][r]);
            }
        }
    }
}

// deg[i] = sum over chunks (u16 hist); block emits partial sum for the scan.
__global__ __launch_bounds__(256) void deg_sum_partials(
    const unsigned short* __restrict__ hist16, int* __restrict__ deg,
    int* __restrict__ partials, int n_nodes, int nchunk) {
    __shared__ int sd[256];
    int b = blockIdx.x, t = threadIdx.x;
    int i = b * 256 + t;
    int s = 0;
    if (i < n_nodes) {
        int r = i >> RSH, ii = i & (RSZ - 1);
        const unsigned short* hp = hist16 + (size_t)r * nchunk * RSZ + ii;
        for (int c = 0; c < nchunk; ++c) s += hp[(size_t)c * RSZ];
        deg[i] = s;
    }
    sd[t] = s;
    __syncthreads();
    for (int st = 128; st > 0; st >>= 1) {
        if (t < st) sd[t] += sd[t + st];
        __syncthreads();
    }
    if (t == 0) partials[b] = sd[0];
}

// One block per 256 nodes: reduce partials locally, Hillis-Steele scan of deg,
// emit row_ptr + inv_deg, and fill base[] (per-cell exclusive offsets) in one pass.
__global__ __launch_bounds__(256) void scan_fill(
    const int* __restrict__ deg, const int* __restrict__ partials,
    const unsigned short* __restrict__ hist16, int* __restrict__ row_ptr,
    float* __restrict__ inv_deg, int* __restrict__ base,
    int n_nodes, int nchunk, int nblk) {
    __shared__ int sp[256];
    __shared__ int sd[256];
    int b = blockIdx.x, t = threadIdx.x;

    sp[t] = (t < b && t < nblk) ? partials[t] : 0;
    __syncthreads();
    for (int st = 128; st > 0; st >>= 1) {
        if (t < st) sp[t] += sp[t + st];
        __syncthreads();
    }
    int pbase = sp[0];

    int i = b * 256 + t;
    int v = (i < n_nodes) ? deg[i] : 0;
    sd[t] = v;
    __syncthreads();
    for (int d = 1; d < 256; d <<= 1) {
        int x = (t >= d) ? sd[t - d] : 0;
        __syncthreads();
        sd[t] += x;
        __syncthreads();
    }
    int excl = sd[t] - v + pbase;
    if (i < n_nodes) {
        row_ptr[i] = excl;
        int dv = v > 1 ? v : 1;
        inv_deg[i] = 1.0f / (float)dv;
        if (i == n_nodes - 1) row_ptr[n_nodes] = excl + v;
        int r = i >> RSH, ii = i & (RSZ - 1);
        int bacc = excl;
        for (int c = 0; c < nchunk; ++c) {
            size_t idx = (size_t)(r * nchunk + c) * RSZ + ii;
            base[idx] = bacc;
            bacc += hist16[idx];
        }
    }
}

// Edge-parallel, atomic-free fill: slot = base[cell] + rank[e].
__global__ __launch_bounds__(256) void fill_edges(
    const int* __restrict__ src, const int* __restrict__ dst,
    const unsigned short* __restrict__ rank, const int* __restrict__ base,
    int* __restrict__ csr, int n_edges, int nchunk) {
    int e = blockIdx.x * 256 + threadIdx.x;
    if (e >= n_edges) return;
    int d = dst[e];
    int c = e >> CSH;
    int r = d >> RSH;
    int slot = base[(size_t)(r * nchunk + c) * RSZ + (d & (RSZ - 1))] + rank[e];
    csr[slot] = src[e];
}

// ---------------- MFMA GEMM (LDS-staged, fused P+Q) -- layers 1,2 ----------------
template <int BN, int NT>
__global__ __launch_bounds__(256) void gemm_lds(
    const unsigned short* __restrict__ Ah, const unsigned short* __restrict__ Al,
    const unsigned short* __restrict__ W1h, const unsigned short* __restrict__ W1l,
    const unsigned short* __restrict__ W2h, const unsigned short* __restrict__ W2l,
    const float* __restrict__ bias, __half* __restrict__ P, float* __restrict__ Q, int M) {
    __shared__ short8 As[2][16 * 65];   // 33.3 KB

    const int tid = threadIdx.x;
    const int wave = tid >> 6;
    const int lane = tid & 63;
    const int l15 = lane & 15;
    const int q = lane >> 4;
    const int m0 = blockIdx.x * 64;

#pragma unroll
    for (int it = 0; it < 8; ++it) {
        int s = it * 256 + tid;          // 0..2047
        int arr = s >> 10;
        int sp = s & 1023;
        int row = sp >> 4, col16 = sp & 15;
        int gr = min(m0 + row, M - 1);
        const unsigned short* src = (arr ? Al : Ah) + (size_t)gr * 128 + col16 * 8;
        As[arr][col16 * 65 + row] = *(const short8*)src;
    }
    __syncthreads();

    const int isQ = wave >> 1;
    const int colbase = (wave & 1) * (NT * 16);
    const unsigned short* Wh = isQ ? W2h : W1h;
    const unsigned short* Wl = isQ ? W2l : W1l;

    float bvs[NT];
#pragma unroll
    for (int nt = 0; nt < NT; ++nt) bvs[nt] = isQ ? bias[colbase + nt * 16 + l15] : 0.f;

    f32x4 acc[4][NT] = {};

#pragma unroll 1
    for (int kt = 0; kt < 4; ++kt) {
        short8 Bh[NT], Bl[NT];
#pragma unroll
        for (int nt = 0; nt < NT; ++nt) {
            int c = colbase + nt * 16 + l15;
            int off = c * 128 + kt * 32 + q * 8;
            Bh[nt] = *(const short8*)(Wh + off);
            Bl[nt] = *(const short8*)(Wl + off);
        }
#pragma unroll
        for (int mt = 0; mt < 4; ++mt) {
            int ai = (kt * 4 + q) * 65 + mt * 16 + l15;
            short8 Afh = As[0][ai];
            short8 Afl = As[1][ai];
#pragma unroll
            for (int nt = 0; nt < NT; ++nt) {
                acc[mt][nt] = __builtin_amdgcn_mfma_f32_16x16x32_bf16(Afh, Bh[nt], acc[mt][nt], 0, 0, 0);
                acc[mt][nt] = __builtin_amdgcn_mfma_f32_16x16x32_bf16(Afh, Bl[nt], acc[mt][nt], 0, 0, 0);
                acc[mt][nt] = __builtin_amdgcn_mfma_f32_16x16x32_bf16(Afl, Bh[nt], acc[mt][nt], 0, 0, 0);
            }
        }
    }

#pragma unroll
    for (int mt = 0; mt < 4; ++mt) {
        int orow = m0 + mt * 16 + q * 4;
#pragma unroll
        for (int nt = 0; nt < NT; ++nt) {
            int col = colbase + nt * 16 + l15;
#pragma unroll
            for (int r = 0; r < 4; ++r) {
                int rr = orow + r;
                if (rr < M) {
                    if (isQ) Q[(size_t)rr * BN + col] = acc[mt][nt][r] + bvs[nt];
                    else P[(size_t)rr * BN + col] = __float2half(acc[mt][nt][r]);
                }
            }
        }
    }
}

// ---------------- fused aggregation 128-dim, fp16 uint4 gather ----------------
// csr indices for the NEXT 8-edge group prefetched during the current group's
// gathers -- breaks the index-load -> gather serial chain. One node per wave
// (R14/R17 lesson: this is the measured concurrency optimum).
__global__ __launch_bounds__(256) void agg_fused128(
    const __half* __restrict__ P, const float* __restrict__ Q,
    const int* __restrict__ row_ptr, const int* __restrict__ csr,
    const float* __restrict__ inv_deg, unsigned short* __restrict__ Hh,
    unsigned short* __restrict__ Hl, int n_nodes) {
    int node = (blockIdx.x * blockDim.x + threadIdx.x) >> 6;
    int lane = threadIdx.x & 63;
    if (node >= n_nodes) return;
    int beg = row_ptr[node], end = row_ptr[node + 1];
    const int g = lane >> 4;    // edge slot 0..3
    const int l = lane & 15;    // 8-col group
    float a[2][8] = {};
    int e = beg;
    bool have = (e + 8 <= end);
    int i0 = 0, i1 = 0;
    if (have) { i0 = csr[e + g]; i1 = csr[e + 4 + g]; }
    while (have) {
        int en = e + 8;
        bool hn = (en + 8 <= end);
        int n0 = 0, n1 = 0;
        if (hn) { n0 = csr[en + g]; n1 = csr[en + 4 + g]; }
        int ss[2] = {i0, i1};
#pragma unroll
        for (int j = 0; j < 2; ++j) {
            uint4 raw = *(const uint4*)(P + (size_t)ss[j] * 128 + l * 8);
            float2 f01 = __half22float2(*reinterpret_cast<__half2*>(&raw.x));
            float2 f23 = __half22float2(*reinterpret_cast<__half2*>(&raw.y));
            float2 f45 = __half22float2(*reinterpret_cast<__half2*>(&raw.z));
            float2 f67 = __half22float2(*reinterpret_cast<__half2*>(&raw.w));
            a[j][0] += f01.x; a[j][1] += f01.y; a[j][2] += f23.x; a[j][3] += f23.y;
            a[j][4] += f45.x; a[j][5] += f45.y; a[j][6] += f67.x; a[j][7] += f67.y;
        }
        e = en; i0 = n0; i1 = n1; have = hn;
    }
    for (; e < end; e += 4) {
        int idx = e + g;
        if (idx < end) {
            int s = csr[idx];
            uint4 raw = *(const uint4*)(P + (size_t)s * 128 + l * 8);
            float2 f01 = __half22float2(*reinterpret_cast<__half2*>(&raw.x));
            float2 f23 = __half22float2(*reinterpret_cast<__half2*>(&raw.y));
            float2 f45 = __half22float2(*reinterpret_cast<__half2*>(&raw.z));
            float2 f67 = __half22float2(*reinterpret_cast<__half2*>(&raw.w));
            a[0][0] += f01.x; a[0][1] += f01.y; a[0][2] += f23.x; a[0][3] += f23.y;
            a[0][4] += f45.x; a[0][5] += f45.y; a[0][6] += f67.x; a[0][7] += f67.y;
        }
    }
    float s[8];
#pragma unroll
    for (int k = 0; k < 8; ++k) {
        s[k] = a[0][k] + a[1][k];
        s[k] += __shfl_xor(s[k], 16);
        s[k] += __shfl_xor(s[k], 32);
    }
    if (lane < 16) {
        float w = inv_deg[node];
        const float4* Q4 = (const float4*)Q;
        float4 q0 = Q4[(size_t)node * 32 + 2 * l];
        float4 q1 = Q4[(size_t)node * 32 + 2 * l + 1];
        float h0 = fmaxf(fmaf(s[0], w, q0.x), 0.f);
        float h1 = fmaxf(fmaf(s[1], w, q0.y), 0.f);
        float h2 = fmaxf(fmaf(s[2], w, q0.z), 0.f);
        float h3 = fmaxf(fmaf(s[3], w, q0.w), 0.f);
        float h4 = fmaxf(fmaf(s[4], w, q1.x), 0.f);
        float h5 = fmaxf(fmaf(s[5], w, q1.y), 0.f);
        float h6 = fmaxf(fmaf(s[6], w, q1.z), 0.f);
        float h7 = fmaxf(fmaf(s[7], w, q1.w), 0.f);
        ushort4 hv0, lv0, hv1, lv1;
        splitf(h0, hv0.x, lv0.x);
        splitf(h1, hv0.y, lv0.y);
        splitf(h2, hv0.z, lv0.z);
        splitf(h3, hv0.w, lv0.w);
        splitf(h4, hv1.x, lv1.x);
        splitf(h5, hv1.y, lv1.y);
        splitf(h6, hv1.z, lv1.z);
        splitf(h7, hv1.w, lv1.w);
        ((ushort4*)Hh)[(size_t)node * 32 + 2 * l] = hv0;
        ((ushort4*)Hh)[(size_t)node * 32 + 2 * l + 1] = hv1;
        ((ushort4*)Hl)[(size_t)node * 32 + 2 * l] = lv0;
        ((ushort4*)Hl)[(size_t)node * 32 + 2 * l + 1] = lv1;
    }
}

// ---------------- fused aggregation 64-dim (fp16 gather) + output head ----------------
__global__ __launch_bounds__(256) void agg64_head(
    const __half* __restrict__ P, const float* __restrict__ Q,
    const int* __restrict__ row_ptr, const int* __restrict__ csr,
    const float* __restrict__ inv_deg, const float* __restrict__ Wo,
    const float* __restrict__ bo, float* __restrict__ out, int n_nodes) {
    int node = (blockIdx.x * blockDim.x + threadIdx.x) >> 6;
    int lane = threadIdx.x & 63;
    if (node >= n_nodes) return;
    int beg = row_ptr[node], end = row_ptr[node + 1];
    const int quarter = lane >> 4;
    const int l = lane & 15;
    float a[2][4] = {};
    int e = beg;
    bool have = (e + 8 <= end);
    int i0 = 0, i1 = 0;
    if (have) { i0 = csr[e + quarter]; i1 = csr[e + 4 + quarter]; }
    while (have) {
        int en = e + 8;
        bool hn = (en + 8 <= end);
        int n0 = 0, n1 = 0;
        if (hn) { n0 = csr[en + quarter]; n1 = csr[en + 4 + quarter]; }
        int ss[2] = {i0, i1};
#pragma unroll
        for (int j = 0; j < 2; ++j) {
            uint2 raw = *(const uint2*)(P + (size_t)ss[j] * 64 + l * 4);
            float2 f01 = __half22float2(*reinterpret_cast<__half2*>(&raw.x));
            float2 f23 = __half22float2(*reinterpret_cast<__half2*>(&raw.y));
            a[j][0] += f01.x; a[j][1] += f01.y; a[j][2] += f23.x; a[j][3] += f23.y;
        }
        e = en; i0 = n0; i1 = n1; have = hn;
    }
    for (; e < end; e += 4) {
        int idx = e + quarter;
        if (idx < end) {
            int s = csr[idx];
            uint2 raw = *(const uint2*)(P + (size_t)s * 64 + l * 4);
            float2 f01 = __half22float2(*reinterpret_cast<__half2*>(&raw.x));
            float2 f23 = __half22float2(*reinterpret_cast<__half2*>(&raw.y));
            a[0][0] += f01.x; a[0][1] += f01.y; a[0][2] += f23.x; a[0][3] += f23.y;
        }
    }
    float s0 = a[0][0] + a[1][0];
    float s1 = a[0][1] + a[1][1];
    float s2 = a[0][2] + a[1][2];
    float s3 = a[0][3] + a[1][3];
    s0 += __shfl_xor(s0, 16); s0 += __shfl_xor(s0, 32);
    s1 += __shfl_xor(s1, 16); s1 += __shfl_xor(s1, 32);
    s2 += __shfl_xor(s2, 16); s2 += __shfl_xor(s2, 32);
    s3 += __shfl_xor(s3, 16); s3 += __shfl_xor(s3, 32);
    if (lane < 16) {
        float w = inv_deg[node];
        float4 qv = ((const float4*)Q)[(size_t)node * 16 + l];
        float h0 = fmaxf(fmaf(s0, w, qv.x), 0.f);
        float h1 = fmaxf(fmaf(s1, w, qv.y), 0.f);
        float h2 = fmaxf(fmaf(s2, w, qv.z), 0.f);
        float h3 = fmaxf(fmaf(s3, w, qv.w), 0.f);
        const float4* Wo4 = (const float4*)Wo;
        float4 w0 = Wo4[4 * l + 0], w1 = Wo4[4 * l + 1], w2 = Wo4[4 * l + 2], w3 = Wo4[4 * l + 3];
        float c0 = h0 * w0.x + h1 * w1.x + h2 * w2.x + h3 * w3.x;
        float c1 = h0 * w0.y + h1 * w1.y + h2 * w2.y + h3 * w3.y;
        float c2 = h0 * w0.z + h1 * w1.z + h2 * w2.z + h3 * w3.z;
        float c3 = h0 * w0.w + h1 * w1.w + h2 * w2.w + h3 * w3.w;
#pragma unroll
        for (int m = 8; m > 0; m >>= 1) {
            c0 += __shfl_xor(c0, m);
            c1 += __shfl_xor(c1, m);
            c2 += __shfl_xor(c2, m);
            c3 += __shfl_xor(c3, m);
        }
        if (l == 0) {
            float4 r;
            r.x = c0 + bo[0];
            r.y = c1 + bo[1];
            r.z = c2 + bo[2];
            r.w = c3 + bo[3];
            ((float4*)out)[node] = r;
        }
    }
}

extern "C" void kernel_launch(void* const* d_in, const int* in_sizes, int n_in,
                              void* d_out, int out_size, void* d_ws, size_t ws_size,
                              hipStream_t stream) {
    const float* x = (const float*)d_in[0];
    const int* ei = (const int*)d_in[1];
    const float* wl0 = (const float*)d_in[3];
    const float* wr0 = (const float*)d_in[4];
    const float* b0 = (const float*)d_in[5];
    const float* wl1 = (const float*)d_in[6];
    const float* wr1 = (const float*)d_in[7];
    const float* b1 = (const float*)d_in[8];
    const float* wl2 = (const float*)d_in[9];
    const float* wr2 = (const float*)d_in[10];
    const float* b2 = (const float*)d_in[11];
    const float* wo = (const float*)d_in[12];
    const float* bo = (const float*)d_in[13];

    const int n_nodes = in_sizes[0] / D;   // 50000
    const int n_edges = in_sizes[1] / 2;   // 800000
    const int* srcp = ei;
    const int* dstp = ei + n_edges;

    char* ws = (char*)d_ws;
    size_t off = 0;
    auto carve = [&](size_t bytes) -> void* {
        void* p = ws + off;
        off = (off + bytes + 255) & ~(size_t)255;
        return p;
    };
    int* deg = (int*)carve((size_t)n_nodes * 4);
    int* row_ptr = (int*)carve((size_t)(n_nodes + 1) * 4);
    int* partials = (int*)carve(256 * 4);
    float* inv_deg = (float*)carve((size_t)n_nodes * 4);
    unsigned short* rankb = (unsigned short*)carve((size_t)n_edges * 2);
    int* csr = (int*)carve((size_t)n_edges * 4);
    __half* Pbuf = (__half*)carve((size_t)n_nodes * D * 2);   // 12.8 MB
    float* Qbuf = (float*)carve((size_t)n_nodes * D * 4);     // 25.6 MB
    unsigned short* hh = (unsigned short*)carve((size_t)n_nodes * D * 2);
    unsigned short* hl = (unsigned short*)carve((size_t)n_nodes * D * 2);
    unsigned short* wt = (unsigned short*)carve((size_t)(4 * 128 * 128 + 2 * 64 * 128) * 2 * 2);
    unsigned short* wl0h = wt;
    unsigned short* wl0l = wl0h + 128 * 128;
    unsigned short* wr0h = wl0l + 128 * 128;
    unsigned short* wr0l = wr0h + 128 * 128;
    unsigned short* wl1h = wr0l + 128 * 128;
    unsigned short* wl1l = wl1h + 128 * 128;
    unsigned short* wr1h = wl1l + 128 * 128;
    unsigned short* wr1l = wr1h + 128 * 128;
    unsigned short* wl2h = wr1l + 128 * 128;
    unsigned short* wl2l = wl2h + 64 * 128;
    unsigned short* wr2h = wl2l + 64 * 128;
    unsigned short* wr2l = wr2h + 64 * 128;

    // hist/base in dedicated scratch (no P/Q aliasing; gemm_x overlaps hist)
    const int nchunk = (n_edges + CSZ - 1) >> CSH;          // 25
    unsigned* hist = (unsigned*)carve((size_t)NRANGE * nchunk * (RSZ / 2) * 4);   // 3.3 MB
    unsigned short* hist16 = (unsigned short*)hist;
    int* basep = (int*)carve((size_t)NRANGE * nchunk * RSZ * 4);                  // 6.6 MB

    const int nblk = (n_nodes + 255) / 256;                 // 196
    const int nhist = NRANGE * nchunk;                      // 100
    const int gemm_blocks = (n_nodes + 63) / 64;            // 782
    const int agg_blocks = (n_nodes * 64 + 255) / 256;

    WSplitArgs wa;
    wa.src[0] = wl0; wa.dh[0] = wl0h; wa.dl[0] = wl0l; wa.n[0] = 128;
    wa.src[1] = wr0; wa.dh[1] = wr0h; wa.dl[1] = wr0l; wa.n[1] = 128;
    wa.src[2] = wl1; wa.dh[2] = wl1h; wa.dl[2] = wl1l; wa.n[2] = 128;
    wa.src[3] = wr1; wa.dh[3] = wr1h; wa.dl[3] = wr1l; wa.n[3] = 128;
    wa.src[4] = wl2; wa.dh[4] = wl2h; wa.dl[4] = wl2l; wa.n[4] = 64;
    wa.src[5] = wr2; wa.dh[5] = wr2h; wa.dl[5] = wr2l; wa.n[5] = 64;

    // 1. split weights (tiny; gemm_x depends on W0 split)
    split_w<<<dim3(64, 6), 256, 0, stream>>>(wa);
    // 2. hist (CSR phase 1, 100 blocks) || layer-0 GEMM (782 blocks)
    hist_gemm_x<<<nhist + gemm_blocks, 1024, 0, stream>>>(
        dstp, hist, rankb, n_edges, nchunk, nhist,
        x, wl0h, wl0l, wr0h, wr0l, b0, Pbuf, Qbuf, n_nodes);
    // 3-5. rest of CSR build
    deg_sum_partials<<<nblk, 256, 0, stream>>>(hist16, deg, partials, n_nodes, nchunk);
    scan_fill<<<nblk, 256, 0, stream>>>(deg, partials, hist16, row_ptr, inv_deg, basep,
                                        n_nodes, nchunk, nblk);
    fill_edges<<<(n_edges + 255) / 256, 256, 0, stream>>>(srcp, dstp, rankb, basep, csr,
                                                          n_edges, nchunk);
    // 6-10. layers
    agg_fused128<<<agg_blocks, 256, 0, stream>>>(Pbuf, Qbuf, row_ptr, csr, inv_deg, hh, hl, n_nodes);
    gemm_lds<128, 4><<<gemm_blocks, 256, 0, stream>>>(
        hh, hl, wl1h, wl1l, wr1h, wr1l, b1, Pbuf, Qbuf, n_nodes);
    agg_fused128<<<agg_blocks, 256, 0, stream>>>(Pbuf, Qbuf, row_ptr, csr, inv_deg, hh, hl, n_nodes);
    gemm_lds<64, 2><<<gemm_blocks, 256, 0, stream>>>(
        hh, hl, wl2h, wl2l, wr2h, wr2l, b2, Pbuf, Qbuf, n_nodes);
    agg64_head<<<agg_blocks, 256, 0, stream>>>(Pbuf, Qbuf, row_ptr, csr, inv_deg,
                                               wo, bo, (float*)d_out, n_nodes);
}